// Round 14
// baseline (681.652 us; speedup 1.0000x reference)
//
#include <hip/hip_runtime.h>
#include <hip/hip_bf16.h>
#include <hip/hip_fp8.h>
#include <stdint.h>

typedef __bf16 bf16x8 __attribute__((ext_vector_type(8)));
typedef __bf16 bf16x4 __attribute__((ext_vector_type(4)));
typedef float  f32x4  __attribute__((ext_vector_type(4)));
typedef int    i32x4  __attribute__((ext_vector_type(4)));
typedef int    i32x8  __attribute__((ext_vector_type(8)));

typedef __attribute__((address_space(3))) unsigned int as3_uint;
typedef const __attribute__((address_space(1))) unsigned int as1_uint;

#define NEGC (-1e9f)

__device__ __forceinline__ void async16(void* ldsPtr, const void* gPtr) {
    __builtin_amdgcn_global_load_lds((as1_uint*)(uintptr_t)gPtr,
                                     (as3_uint*)(uintptr_t)ldsPtr, 16, 0, 0);
}

// -------- LayerNorm + gate, fused: f32 in -> fp8 xn8 + gate probs Gp ---------
// bf16 xn is DEAD (attn & LM consume fp8); gate re-read of xn eliminated --
// the row is already in this block's registers. Gate math identical to the
// old gate_kernel (same xr[16][65] staging, same reduction, same softmax).
__global__ __launch_bounds__(256) void ln_gate_kernel(const float* __restrict__ x,
                                                      const float* __restrict__ gw,
                                                      const float* __restrict__ bw,
                                                      const float* __restrict__ Wg,
                                                      const float* __restrict__ gb,
                                                      unsigned char* __restrict__ xn8,
                                                      float* __restrict__ Gp) {
    __shared__ float red[8];
    __shared__ float xr[16][65];
    __shared__ float red2[16][17];
    size_t row = blockIdx.x;
    int t = threadIdx.x;
    const float4* xrp = (const float4*)(x + row * 1024);
    float4 v = xrp[t];
    float s  = v.x + v.y + v.z + v.w;
    float ss = v.x*v.x + v.y*v.y + v.z*v.z + v.w*v.w;
    #pragma unroll
    for (int o = 32; o; o >>= 1) { s += __shfl_xor(s, o); ss += __shfl_xor(ss, o); }
    int wave = t >> 6, lane = t & 63;
    if (lane == 0) { red[wave*2] = s; red[wave*2+1] = ss; }
    __syncthreads();
    float S  = red[0] + red[2] + red[4] + red[6];
    float SS = red[1] + red[3] + red[5] + red[7];
    float mu  = S * (1.0f/1024.0f);
    float var = SS * (1.0f/1024.0f) - mu*mu;
    float rs  = rsqrtf(var + 1e-5f);
    float4 gv = ((const float4*)gw)[t];
    float4 bv = ((const float4*)bw)[t];
    float f0 = (v.x-mu)*rs*gv.x + bv.x;
    float f1 = (v.y-mu)*rs*gv.y + bv.y;
    float f2 = (v.z-mu)*rs*gv.z + bv.z;
    float f3 = (v.w-mu)*rs*gv.w + bv.w;
    unsigned int pk = (unsigned)__hip_fp8_e4m3(f0).__x
                    | ((unsigned)__hip_fp8_e4m3(f1).__x << 8)
                    | ((unsigned)__hip_fp8_e4m3(f2).__x << 16)
                    | ((unsigned)__hip_fp8_e4m3(f3).__x << 24);
    ((unsigned int*)(xn8 + row*1024))[t] = pk;
    // gate: stage normalized row to LDS (same layout the old gate_kernel used)
    {
        int e = t*4;
        xr[e >> 6][ e       & 63] = f0;
        xr[e >> 6][(e + 1)  & 63] = f1;
        xr[e >> 6][(e + 2)  & 63] = f2;
        xr[e >> 6][(e + 3)  & 63] = f3;
    }
    __syncthreads();
    int h = t & 15, sl = t >> 4;
    float p = 0.f;
    #pragma unroll
    for (int u = 0; u < 64; ++u) p += xr[sl][u] * Wg[(sl*64 + u)*16 + h];
    red2[sl][h] = p;
    __syncthreads();
    if (t < 16) {
        float logit = gb[t];
        #pragma unroll
        for (int s2 = 0; s2 < 16; ++s2) logit += red2[s2][t];
        float m = logit;
        #pragma unroll
        for (int o = 8; o; o >>= 1) m = fmaxf(m, __shfl_xor(m, o, 16));
        float e = __expf(logit - m);
        float ssum = e;
        #pragma unroll
        for (int o = 8; o; o >>= 1) ssum += __shfl_xor(ssum, o, 16);
        Gp[row*16 + t] = e / ssum;
    }
}

// ---------------- PHM weight builder: W^T fp8 e4m3 of (val*16) ----------------
// x16 lifts W (std~0.014-0.02) out of e4m3 subnormal range; the MX GEMM
// epilogue multiplies acc by 1/16.
__global__ __launch_bounds__(256) void phm_build8(const float* __restrict__ A,
                                                  const float* __restrict__ S,
                                                  unsigned char* __restrict__ Wt,
                                                  int nn, int kin, int kout) {
    __shared__ float sh[4][32][65];
    __shared__ float shA[64];
    int t  = threadIdx.x;
    int l0 = blockIdx.x * 64;
    int k0 = blockIdx.y * 32;
    int kt = nn * kin;  // 1024
    if (t < nn*nn*nn) shA[t] = A[t];
    for (int n = 0; n < nn; ++n) {
        #pragma unroll
        for (int i = 0; i < 8; ++i) {
            int e = t + i*256;
            int kk = e >> 6, ll = e & 63;
            sh[n][kk][ll] = S[((size_t)(n*kin) + k0 + kk)*kout + l0 + ll];
        }
    }
    __syncthreads();
    for (int a = 0; a < nn; ++a)
        for (int b = 0; b < nn; ++b) {
            #pragma unroll
            for (int i = 0; i < 8; ++i) {
                int e = t + i*256;
                int kk = e & 31, ll = e >> 5;
                float val = 0.f;
                for (int n = 0; n < nn; ++n)
                    val += shA[(n*nn + a)*nn + b] * sh[n][kk][ll];
                size_t idx = (size_t)(b*kout + l0 + ll)*kt + a*kin + k0 + kk;
                Wt[idx] = __hip_fp8_e4m3(val * 16.0f).__x;
            }
        }
}

// ---------------- gate weight (1024 x 16) f32 ----------------
__global__ __launch_bounds__(256) void gatew_kernel(const float* __restrict__ A,
                                                    const float* __restrict__ S,
                                                    float* __restrict__ W) {
    int idx = blockIdx.x*256 + threadIdx.x;      // 16384 total
    int r = idx >> 4, c = idx & 15;
    int a = r >> 8, k = r & 255, b = c >> 2, l = c & 3;
    float v = 0.f;
    #pragma unroll
    for (int n = 0; n < 4; ++n)
        v += A[(n*4 + a)*4 + b] * S[((size_t)(n*256 + k))*4 + l];
    W[idx] = v;
}

// ---------------- MX-fp8 GEMM (mfma_scale 16x16x128, scale=2^0) ---------------
// m97 128^2 structure (measured: LM ~229us, attn-MX confirmed r13).
// A8 (M x K fp8), B8 (N x K fp8, = W^T x16). Epilogue: acc * 1/16 + bias.
// SWZ==1: LM geometry (32 m-tiles x 250 n-tiles, 8000 blocks 1D, XCD bands).
// SWZ==0: 2D grid (x = n-tile, y = m-tile).
// OUTMODE 0: f32 rows width N.  OUTMODE 1: bf16 at FRONT of f32 row slot.
template<int SWZ, int OUTMODE>
__global__ __launch_bounds__(256) void gemm_mx(const unsigned char* __restrict__ A8,
                                               const unsigned char* __restrict__ B8,
                                               const float* __restrict__ bias,
                                               void* __restrict__ Cv,
                                               int N, int K) {
    __shared__ __align__(16) unsigned char As[128*128];   // 16 KB
    __shared__ __align__(16) unsigned char Bs[128*128];   // 16 KB
    int tid = threadIdx.x;
    int wave = tid >> 6, lane = tid & 63;
    int m0, n0;
    if (SWZ) {
        int bid  = blockIdx.x;
        int wg   = (bid & 7) * 1000 + (bid >> 3);   // XCD-contiguous chunks
        int band = wg / 2000;                        // 4 bands of 8 m-tiles
        int rem  = wg % 2000;
        m0 = (band * 8 + (rem & 7)) * 128;
        n0 = (rem >> 3) * 128;
    } else {
        m0 = blockIdx.y * 128; n0 = blockIdx.x * 128;
    }
    int wm = (wave >> 1) * 64, wn = (wave & 1) * 64;
    int lrow = lane & 15, lk = lane >> 4;
    f32x4 acc[4][4] = {};
    for (int k0 = 0; k0 < K; k0 += 128) {
        #pragma unroll
        for (int q = 0; q < 4; ++q) {
            int o = q*4096 + tid*16;
            int r = o >> 7;                      // row 0..127
            int p = (o >> 4) & 7;                // linear chunk pos
            int g = p ^ (r & 7);                 // pre-swizzled source chunk
            async16((char*)As + q*4096 + wave*1024,
                    (const char*)A8 + (size_t)(m0+r)*K + k0 + g*16);
            async16((char*)Bs + q*4096 + wave*1024,
                    (const char*)B8 + (size_t)(n0+r)*K + k0 + g*16);
        }
        __syncthreads();
        i32x8 af[4], bfr[4];
        #pragma unroll
        for (int mi = 0; mi < 4; ++mi) {         // A row r, k-bytes lk*32..+31
            int r = wm + mi*16 + lrow;
            int c0 = lk*2;
            i32x4 lo = *(const i32x4*)(As + r*128 + ((c0    ^ (r&7))*16));
            i32x4 hi = *(const i32x4*)(As + r*128 + (((c0+1) ^ (r&7))*16));
            af[mi] = __builtin_shufflevector(lo, hi, 0,1,2,3,4,5,6,7);
        }
        #pragma unroll
        for (int ni = 0; ni < 4; ++ni) {
            int r = wn + ni*16 + lrow;
            int c0 = lk*2;
            i32x4 lo = *(const i32x4*)(Bs + r*128 + ((c0    ^ (r&7))*16));
            i32x4 hi = *(const i32x4*)(Bs + r*128 + (((c0+1) ^ (r&7))*16));
            bfr[ni] = __builtin_shufflevector(lo, hi, 0,1,2,3,4,5,6,7);
        }
        #pragma unroll
        for (int mi = 0; mi < 4; ++mi)
            #pragma unroll
            for (int ni = 0; ni < 4; ++ni)
                acc[mi][ni] = __builtin_amdgcn_mfma_scale_f32_16x16x128_f8f6f4(
                    af[mi], bfr[ni], acc[mi][ni],
                    0 /*A=fp8*/, 0 /*B=fp8*/, 0, 127, 0, 127);  // scale=2^0
        __syncthreads();
    }
    #pragma unroll
    for (int ni = 0; ni < 4; ++ni) {
        int col = n0 + wn + ni*16 + lrow;
        float bv = bias ? bias[col] : 0.f;
        #pragma unroll
        for (int mi = 0; mi < 4; ++mi) {
            #pragma unroll
            for (int r = 0; r < 4; ++r) {
                int rowg = m0 + wm + mi*16 + lk*4 + r;   // C/D: col=lane&15, row=(lane>>4)*4+reg
                float val = acc[mi][ni][r] * 0.0625f + bv;     // undo W x16
                if (OUTMODE == 1)
                    ((__bf16*)((char*)Cv + (size_t)rowg * N * 4))[col] = (__bf16)val;
                else
                    ((float*)Cv)[(size_t)rowg * N + col] = val;
            }
        }
    }
}

// ---------------- scores v3 (r8/r11/r13-proven): 256 thr x 2 j; XCD-local -----
__global__ __launch_bounds__(256) void scores_kernel(const float* __restrict__ qk,
                                                     const float* __restrict__ Gp,
                                                     const int* __restrict__ lens,
                                                     float* __restrict__ out) {
    __shared__ float qs[8][1024];
    __shared__ float gps[8][16];
    __shared__ float wredB[2][4][8];
    int bid = blockIdx.x;
    int b   = bid & 7;
    int i0  = (bid >> 3) * 8;
    int t   = threadIdx.x;
    int wave = t >> 6, lane = t & 63;
    int len = lens[b];
    const float4* qbase = (const float4*)(qk + ((size_t)b*512 + i0)*2048);
    #pragma unroll
    for (int s = 0; s < 8; ++s) {
        int e = t + s*256;
        int ti = e >> 8, c4 = e & 255;
        ((float4*)qs)[e] = qbase[ti*512 + c4];
    }
    if (t < 128) gps[t >> 4][t & 15] = Gp[((size_t)b*512 + i0 + (t >> 4))*16 + (t & 15)];
    __syncthreads();
    int j0 = t, j1 = t + 256;
    const float4* kp0 = (const float4*)(qk + ((size_t)b*512 + j0)*2048 + 1024);
    const float4* kp1 = (const float4*)(qk + ((size_t)b*512 + j1)*2048 + 1024);
    float acc0[8] = {}, acc1[8] = {}, mace[8] = {};
    for (int h = 0; h < 16; ++h) {
        float4 kv0[16], kv1[16];
        #pragma unroll
        for (int u = 0; u < 16; ++u) { kv0[u] = kp0[h*16 + u]; kv1[u] = kp1[h*16 + u]; }
        float pex0[8], pex1[8];
        #pragma unroll
        for (int ti = 0; ti < 8; ++ti) {
            const float* qrow = &qs[ti][h*64];
            float d0 = 0.f, d1 = 0.f;
            #pragma unroll
            for (int u = 0; u < 16; ++u) {
                float q0 = qrow[u*4+0], q1 = qrow[u*4+1], q2 = qrow[u*4+2], q3 = qrow[u*4+3];
                d0 += kv0[u].x*q0 + kv0[u].y*q1 + kv0[u].z*q2 + kv0[u].w*q3;
                d1 += kv1[u].x*q0 + kv1[u].y*q1 + kv1[u].z*q2 + kv1[u].w*q3;
            }
            int i = i0 + ti;
            float sc0 = (j0 > i && j0 < len) ? d0 * 0.125f : NEGC;
            float sc1 = (j1 > i && j1 < len) ? d1 * 0.125f : NEGC;
            float pe0 = __expf(sc0), pe1 = __expf(sc1);   // exp(NEG)=0 for invalid j
            pex0[ti] = pe0; pex1[ti] = pe1;
            float vv = pe0 + pe1;
            #pragma unroll
            for (int o = 32; o; o >>= 1) vv += __shfl_xor(vv, o);
            if (lane == 0) wredB[h & 1][wave][ti] = vv;
        }
        __syncthreads();
        #pragma unroll
        for (int ti = 0; ti < 8; ++ti) {
            float gs = wredB[h & 1][0][ti] + wredB[h & 1][1][ti]
                     + wredB[h & 1][2][ti] + wredB[h & 1][3][ti];
            float inv = 1.0f / gs;
            float g = gps[ti][h];
            acc0[ti] += pex0[ti] * inv * g;
            acc1[ti] += pex1[ti] * inv * g;
            mace[ti] += g * inv;
        }
    }
    #pragma unroll
    for (int ti = 0; ti < 8; ++ti) {
        int i = i0 + ti;
        float lm = NEGC + __logf(mace[ti]);
        float v0, v1;
        if (i >= len - 1) { v0 = NEGC; v1 = NEGC; }
        else {
            v0 = (j0 > i && j0 < len) ? __logf(acc0[ti]) : lm;
            v1 = (j1 > i && j1 < len) ? __logf(acc1[ti]) : lm;
        }
        out[((size_t)b*512 + i)*512 + j0] = v0;
        out[((size_t)b*512 + i)*512 + j1] = v1;
    }
}

// ---------------- vocab v2: bf16 logits -> in-place f32 log-softmax -----------
// ZERO LDS (row in 64 VGPR/thread); near the 786MB HBM floor (r11).
__global__ __launch_bounds__(256) void vocab_softmax_bf16(float* __restrict__ out) {
    __shared__ float red[8];
    size_t row = blockIdx.x;
    char* rowbase = (char*)out + row * (size_t)32000 * 4;
    const bf16x8* g8 = (const bf16x8*)rowbase;
    int t = threadIdx.x, wave = t >> 6, lane = t & 63;
    bf16x8 cc[16];
    float mx = -1e30f;
    #pragma unroll
    for (int s = 0; s < 16; ++s) {
        int v = t + s*256;
        if (v < 4000) {
            cc[s] = g8[v];
            #pragma unroll
            for (int jj = 0; jj < 8; ++jj) mx = fmaxf(mx, (float)cc[s][jj]);
        }
    }
    #pragma unroll
    for (int o = 32; o; o >>= 1) mx = fmaxf(mx, __shfl_xor(mx, o));
    if (lane == 0) red[wave] = mx;
    __syncthreads();
    mx = fmaxf(fmaxf(red[0], red[1]), fmaxf(red[2], red[3]));
    float sum = 0.f;
    #pragma unroll
    for (int s = 0; s < 16; ++s) {
        int v = t + s*256;
        if (v < 4000) {
            #pragma unroll
            for (int jj = 0; jj < 8; ++jj) sum += __expf((float)cc[s][jj] - mx);
        }
    }
    #pragma unroll
    for (int o = 32; o; o >>= 1) sum += __shfl_xor(sum, o);
    if (lane == 0) red[4 + wave] = sum;
    __syncthreads();               // also orders ALL reads before writes below
    float lse = mx + __logf(red[4] + red[5] + red[6] + red[7]);
    float4* o4 = (float4*)rowbase;
    #pragma unroll
    for (int s = 0; s < 16; ++s) {
        int v = t + s*256;
        if (v < 4000) {
            float4 a, b;
            a.x = (float)cc[s][0] - lse; a.y = (float)cc[s][1] - lse;
            a.z = (float)cc[s][2] - lse; a.w = (float)cc[s][3] - lse;
            b.x = (float)cc[s][4] - lse; b.y = (float)cc[s][5] - lse;
            b.z = (float)cc[s][6] - lse; b.w = (float)cc[s][7] - lse;
            o4[v*2]   = a;
            o4[v*2+1] = b;
        }
    }
}

extern "C" void kernel_launch(void* const* d_in, const int* in_sizes, int n_in,
                              void* d_out, int out_size, void* d_ws, size_t ws_size,
                              hipStream_t stream) {
    (void)in_sizes; (void)n_in; (void)out_size; (void)ws_size;
    const float* x      = (const float*)d_in[0];
    const int*   lens   = (const int*)  d_in[1];
    const float* ln_g   = (const float*)d_in[2];
    const float* ln_b   = (const float*)d_in[3];
    const float* attn_A = (const float*)d_in[4];
    const float* attn_S = (const float*)d_in[5];
    const float* attn_b = (const float*)d_in[6];
    const float* gate_A = (const float*)d_in[7];
    const float* gate_S = (const float*)d_in[8];
    const float* gate_b = (const float*)d_in[9];
    const float* lm_A   = (const float*)d_in[10];
    const float* lm_S   = (const float*)d_in[11];
    const float* lm_b   = (const float*)d_in[12];

    float* out_trans = (float*)d_out;
    float* out_vocab = out_trans + (size_t)8*512*512;

    char* ws = (char*)d_ws;
    unsigned char* xn8     = (unsigned char*)(ws);            //  4,194,304 B (fp8)
    unsigned char* WtAttn8 = (unsigned char*)(ws + 4194304);  //  2,097,152 B (fp8 x16)
    unsigned char* WtLm8   = (unsigned char*)(ws + 6291456);  // 32,768,000 B (fp8 x16)
    float*         Wg      = (float*)(ws + 39059456);         //     65,536 B
    float*         qkbuf   = (float*)(ws + 39124992);         // 33,554,432 B
    float*         Gp      = (float*)(ws + 72679424);         //    262,144 B

    hipLaunchKernelGGL(gatew_kernel, dim3(64),       dim3(256), 0, stream, gate_A, gate_S, Wg);
    hipLaunchKernelGGL(ln_gate_kernel, dim3(4096),   dim3(256), 0, stream,
                       x, ln_g, ln_b, Wg, gate_b, xn8, Gp);
    hipLaunchKernelGGL(phm_build8,   dim3(8, 8),     dim3(256), 0, stream, attn_A, attn_S, WtAttn8, 4, 256, 512);
    hipLaunchKernelGGL(phm_build8,   dim3(250, 16),  dim3(256), 0, stream, lm_A, lm_S, WtLm8, 2, 512, 16000);
    hipLaunchKernelGGL((gemm_mx<0,0>), dim3(16, 32), dim3(256), 0, stream,
                       xn8, WtAttn8, attn_b, (void*)qkbuf, 2048, 1024);
    hipLaunchKernelGGL(scores_kernel,dim3(512),      dim3(256), 0, stream, qkbuf, Gp, lens, out_trans);
    hipLaunchKernelGGL((gemm_mx<1,1>), dim3(8000),   dim3(256), 0, stream,
                       xn8, WtLm8, lm_b, (void*)out_vocab, 32000, 1024);
    hipLaunchKernelGGL(vocab_softmax_bf16, dim3(4096), dim3(256), 0, stream, out_vocab);
}

// Round 15
// 672.364 us; speedup vs baseline: 1.0138x; 1.0138x over previous
//
#include <hip/hip_runtime.h>
#include <hip/hip_bf16.h>
#include <hip/hip_fp8.h>
#include <stdint.h>

typedef __bf16 bf16x8 __attribute__((ext_vector_type(8)));
typedef __bf16 bf16x4 __attribute__((ext_vector_type(4)));
typedef float  f32x4  __attribute__((ext_vector_type(4)));
typedef int    i32x4  __attribute__((ext_vector_type(4)));
typedef int    i32x8  __attribute__((ext_vector_type(8)));

typedef __attribute__((address_space(3))) unsigned int as3_uint;
typedef const __attribute__((address_space(1))) unsigned int as1_uint;

#define NEGC (-1e9f)

__device__ __forceinline__ void async16(void* ldsPtr, const void* gPtr) {
    __builtin_amdgcn_global_load_lds((as1_uint*)(uintptr_t)gPtr,
                                     (as3_uint*)(uintptr_t)ldsPtr, 16, 0, 0);
}

// ---------------- LayerNorm: f32 in -> bf16 xn AND fp8(e4m3) xn8 ----------------
__global__ __launch_bounds__(256) void ln_kernel(const float* __restrict__ x,
                                                 const float* __restrict__ gw,
                                                 const float* __restrict__ bw,
                                                 __bf16* __restrict__ xn,
                                                 unsigned char* __restrict__ xn8) {
    __shared__ float red[8];
    size_t row = blockIdx.x;
    int t = threadIdx.x;
    const float4* xr = (const float4*)(x + row * 1024);
    float4 v = xr[t];
    float s  = v.x + v.y + v.z + v.w;
    float ss = v.x*v.x + v.y*v.y + v.z*v.z + v.w*v.w;
    #pragma unroll
    for (int o = 32; o; o >>= 1) { s += __shfl_xor(s, o); ss += __shfl_xor(ss, o); }
    int wave = t >> 6, lane = t & 63;
    if (lane == 0) { red[wave*2] = s; red[wave*2+1] = ss; }
    __syncthreads();
    float S  = red[0] + red[2] + red[4] + red[6];
    float SS = red[1] + red[3] + red[5] + red[7];
    float mu  = S * (1.0f/1024.0f);
    float var = SS * (1.0f/1024.0f) - mu*mu;
    float rs  = rsqrtf(var + 1e-5f);
    float4 gv = ((const float4*)gw)[t];
    float4 bv = ((const float4*)bw)[t];
    float f0 = (v.x-mu)*rs*gv.x + bv.x;
    float f1 = (v.y-mu)*rs*gv.y + bv.y;
    float f2 = (v.z-mu)*rs*gv.z + bv.z;
    float f3 = (v.w-mu)*rs*gv.w + bv.w;
    bf16x4 o4;
    o4[0] = (__bf16)f0; o4[1] = (__bf16)f1; o4[2] = (__bf16)f2; o4[3] = (__bf16)f3;
    ((bf16x4*)(xn + row*1024))[t] = o4;
    unsigned int pk = (unsigned)__hip_fp8_e4m3(f0).__x
                    | ((unsigned)__hip_fp8_e4m3(f1).__x << 8)
                    | ((unsigned)__hip_fp8_e4m3(f2).__x << 16)
                    | ((unsigned)__hip_fp8_e4m3(f3).__x << 24);
    ((unsigned int*)(xn8 + row*1024))[t] = pk;
}

// ---------------- PHM weight builder: W^T (nn*kout rows x nn*kin cols) --------
// OUT==0: bf16. OUT==1: fp8 e4m3 of (val*16) -- x16 lifts W (std~0.014-0.02)
// out of e4m3 subnormal range; the MX GEMM epilogue multiplies acc by 1/16.
template<int OUT>
__global__ __launch_bounds__(256) void phm_build(const float* __restrict__ A,
                                                 const float* __restrict__ S,
                                                 void* __restrict__ Wt,
                                                 int nn, int kin, int kout) {
    __shared__ float sh[4][32][65];
    __shared__ float shA[64];
    int t  = threadIdx.x;
    int l0 = blockIdx.x * 64;
    int k0 = blockIdx.y * 32;
    int kt = nn * kin;  // 1024
    if (t < nn*nn*nn) shA[t] = A[t];
    for (int n = 0; n < nn; ++n) {
        #pragma unroll
        for (int i = 0; i < 8; ++i) {
            int e = t + i*256;
            int kk = e >> 6, ll = e & 63;
            sh[n][kk][ll] = S[((size_t)(n*kin) + k0 + kk)*kout + l0 + ll];
        }
    }
    __syncthreads();
    for (int a = 0; a < nn; ++a)
        for (int b = 0; b < nn; ++b) {
            #pragma unroll
            for (int i = 0; i < 8; ++i) {
                int e = t + i*256;
                int kk = e & 31, ll = e >> 5;
                float val = 0.f;
                for (int n = 0; n < nn; ++n)
                    val += shA[(n*nn + a)*nn + b] * sh[n][kk][ll];
                size_t idx = (size_t)(b*kout + l0 + ll)*kt + a*kin + k0 + kk;
                if (OUT == 0) ((__bf16*)Wt)[idx] = (__bf16)val;
                else          ((unsigned char*)Wt)[idx] = __hip_fp8_e4m3(val * 16.0f).__x;
            }
        }
}

// ---------------- gate weight (1024 x 16) f32 ----------------
__global__ __launch_bounds__(256) void gatew_kernel(const float* __restrict__ A,
                                                    const float* __restrict__ S,
                                                    float* __restrict__ W) {
    int idx = blockIdx.x*256 + threadIdx.x;      // 16384 total
    int r = idx >> 4, c = idx & 15;
    int a = r >> 8, k = r & 255, b = c >> 2, l = c & 3;
    float v = 0.f;
    #pragma unroll
    for (int n = 0; n < 4; ++n)
        v += A[(n*4 + a)*4 + b] * S[((size_t)(n*256 + k))*4 + l];
    W[idx] = v;
}

// ---------------- MX-fp8 GEMM (mfma_scale 16x16x128, scale=2^0) ---------------
// m97 128^2 structure (r10/r13 measured: LM ~226us, attn confirmed -20us).
// A8 (M x K fp8), B8 (N x K fp8, = W^T x16). Epilogue: acc * 1/16 + bias.
// SWZ==1: LM geometry (32 m-tiles x 250 n-tiles, 8000 blocks 1D, XCD bands).
// SWZ==0: 2D grid (x = n-tile, y = m-tile).
// OUTMODE 0: f32 rows width N.  OUTMODE 1: bf16 at FRONT of f32 row slot.
template<int SWZ, int OUTMODE>
__global__ __launch_bounds__(256) void gemm_mx(const unsigned char* __restrict__ A8,
                                               const unsigned char* __restrict__ B8,
                                               const float* __restrict__ bias,
                                               void* __restrict__ Cv,
                                               int N, int K) {
    __shared__ __align__(16) unsigned char As[128*128];   // 16 KB
    __shared__ __align__(16) unsigned char Bs[128*128];   // 16 KB
    int tid = threadIdx.x;
    int wave = tid >> 6, lane = tid & 63;
    int m0, n0;
    if (SWZ) {
        int bid  = blockIdx.x;
        int wg   = (bid & 7) * 1000 + (bid >> 3);   // XCD-contiguous chunks
        int band = wg / 2000;                        // 4 bands of 8 m-tiles
        int rem  = wg % 2000;
        m0 = (band * 8 + (rem & 7)) * 128;
        n0 = (rem >> 3) * 128;
    } else {
        m0 = blockIdx.y * 128; n0 = blockIdx.x * 128;
    }
    int wm = (wave >> 1) * 64, wn = (wave & 1) * 64;
    int lrow = lane & 15, lk = lane >> 4;
    f32x4 acc[4][4] = {};
    for (int k0 = 0; k0 < K; k0 += 128) {
        #pragma unroll
        for (int q = 0; q < 4; ++q) {
            int o = q*4096 + tid*16;
            int r = o >> 7;                      // row 0..127
            int p = (o >> 4) & 7;                // linear chunk pos
            int g = p ^ (r & 7);                 // pre-swizzled source chunk
            async16((char*)As + q*4096 + wave*1024,
                    (const char*)A8 + (size_t)(m0+r)*K + k0 + g*16);
            async16((char*)Bs + q*4096 + wave*1024,
                    (const char*)B8 + (size_t)(n0+r)*K + k0 + g*16);
        }
        __syncthreads();
        i32x8 af[4], bfr[4];
        #pragma unroll
        for (int mi = 0; mi < 4; ++mi) {         // A row r, k-bytes lk*32..+31
            int r = wm + mi*16 + lrow;
            int c0 = lk*2;
            i32x4 lo = *(const i32x4*)(As + r*128 + ((c0    ^ (r&7))*16));
            i32x4 hi = *(const i32x4*)(As + r*128 + (((c0+1) ^ (r&7))*16));
            af[mi] = __builtin_shufflevector(lo, hi, 0,1,2,3,4,5,6,7);
        }
        #pragma unroll
        for (int ni = 0; ni < 4; ++ni) {
            int r = wn + ni*16 + lrow;
            int c0 = lk*2;
            i32x4 lo = *(const i32x4*)(Bs + r*128 + ((c0    ^ (r&7))*16));
            i32x4 hi = *(const i32x4*)(Bs + r*128 + (((c0+1) ^ (r&7))*16));
            bfr[ni] = __builtin_shufflevector(lo, hi, 0,1,2,3,4,5,6,7);
        }
        #pragma unroll
        for (int mi = 0; mi < 4; ++mi)
            #pragma unroll
            for (int ni = 0; ni < 4; ++ni)
                acc[mi][ni] = __builtin_amdgcn_mfma_scale_f32_16x16x128_f8f6f4(
                    af[mi], bfr[ni], acc[mi][ni],
                    0 /*A=fp8*/, 0 /*B=fp8*/, 0, 127, 0, 127);  // scale=2^0
        __syncthreads();
    }
    #pragma unroll
    for (int ni = 0; ni < 4; ++ni) {
        int col = n0 + wn + ni*16 + lrow;
        float bv = bias ? bias[col] : 0.f;
        #pragma unroll
        for (int mi = 0; mi < 4; ++mi) {
            #pragma unroll
            for (int r = 0; r < 4; ++r) {
                int rowg = m0 + wm + mi*16 + lk*4 + r;   // C/D: col=lane&15, row=(lane>>4)*4+reg
                float val = acc[mi][ni][r] * 0.0625f + bv;     // undo W x16
                if (OUTMODE == 1)
                    ((__bf16*)((char*)Cv + (size_t)rowg * N * 4))[col] = (__bf16)val;
                else
                    ((float*)Cv)[(size_t)rowg * N + col] = val;
            }
        }
    }
}

// ---------------- gate: logits + softmax probs Gp (4096 x 16) ----------------
__global__ __launch_bounds__(256) void gate_kernel(const __bf16* __restrict__ xn,
                                                   const float* __restrict__ Wg,
                                                   const float* __restrict__ gb,
                                                   float* __restrict__ Gp) {
    __shared__ float xr[16][65];
    __shared__ float red[16][17];
    size_t row = blockIdx.x;
    int t = threadIdx.x;
    bf16x4 v = ((const bf16x4*)(xn + row*1024))[t];
    #pragma unroll
    for (int q = 0; q < 4; ++q) {
        int e = t*4 + q;
        xr[e >> 6][e & 63] = (float)v[q];
    }
    __syncthreads();
    int h = t & 15, sl = t >> 4;
    float p = 0.f;
    #pragma unroll
    for (int u = 0; u < 64; ++u) p += xr[sl][u] * Wg[(sl*64 + u)*16 + h];
    red[sl][h] = p;
    __syncthreads();
    if (t < 16) {
        float logit = gb[t];
        #pragma unroll
        for (int s2 = 0; s2 < 16; ++s2) logit += red[s2][t];
        float m = logit;
        #pragma unroll
        for (int o = 8; o; o >>= 1) m = fmaxf(m, __shfl_xor(m, o, 16));
        float e = __expf(logit - m);
        float ssum = e;
        #pragma unroll
        for (int o = 8; o; o >>= 1) ssum += __shfl_xor(ssum, o, 16);
        Gp[row*16 + t] = e / ssum;
    }
}

// ---------------- scores v3 (r8/r11/r13-proven): 256 thr x 2 j; XCD-local -----
__global__ __launch_bounds__(256) void scores_kernel(const float* __restrict__ qk,
                                                     const float* __restrict__ Gp,
                                                     const int* __restrict__ lens,
                                                     float* __restrict__ out) {
    __shared__ float qs[8][1024];
    __shared__ float gps[8][16];
    __shared__ float wredB[2][4][8];
    int bid = blockIdx.x;
    int b   = bid & 7;
    int i0  = (bid >> 3) * 8;
    int t   = threadIdx.x;
    int wave = t >> 6, lane = t & 63;
    int len = lens[b];
    const float4* qbase = (const float4*)(qk + ((size_t)b*512 + i0)*2048);
    #pragma unroll
    for (int s = 0; s < 8; ++s) {
        int e = t + s*256;
        int ti = e >> 8, c4 = e & 255;
        ((float4*)qs)[e] = qbase[ti*512 + c4];
    }
    if (t < 128) gps[t >> 4][t & 15] = Gp[((size_t)b*512 + i0 + (t >> 4))*16 + (t & 15)];
    __syncthreads();
    int j0 = t, j1 = t + 256;
    const float4* kp0 = (const float4*)(qk + ((size_t)b*512 + j0)*2048 + 1024);
    const float4* kp1 = (const float4*)(qk + ((size_t)b*512 + j1)*2048 + 1024);
    float acc0[8] = {}, acc1[8] = {}, mace[8] = {};
    for (int h = 0; h < 16; ++h) {
        float4 kv0[16], kv1[16];
        #pragma unroll
        for (int u = 0; u < 16; ++u) { kv0[u] = kp0[h*16 + u]; kv1[u] = kp1[h*16 + u]; }
        float pex0[8], pex1[8];
        #pragma unroll
        for (int ti = 0; ti < 8; ++ti) {
            const float* qrow = &qs[ti][h*64];
            float d0 = 0.f, d1 = 0.f;
            #pragma unroll
            for (int u = 0; u < 16; ++u) {
                float q0 = qrow[u*4+0], q1 = qrow[u*4+1], q2 = qrow[u*4+2], q3 = qrow[u*4+3];
                d0 += kv0[u].x*q0 + kv0[u].y*q1 + kv0[u].z*q2 + kv0[u].w*q3;
                d1 += kv1[u].x*q0 + kv1[u].y*q1 + kv1[u].z*q2 + kv1[u].w*q3;
            }
            int i = i0 + ti;
            float sc0 = (j0 > i && j0 < len) ? d0 * 0.125f : NEGC;
            float sc1 = (j1 > i && j1 < len) ? d1 * 0.125f : NEGC;
            float pe0 = __expf(sc0), pe1 = __expf(sc1);   // exp(NEG)=0 for invalid j
            pex0[ti] = pe0; pex1[ti] = pe1;
            float vv = pe0 + pe1;
            #pragma unroll
            for (int o = 32; o; o >>= 1) vv += __shfl_xor(vv, o);
            if (lane == 0) wredB[h & 1][wave][ti] = vv;
        }
        __syncthreads();
        #pragma unroll
        for (int ti = 0; ti < 8; ++ti) {
            float gs = wredB[h & 1][0][ti] + wredB[h & 1][1][ti]
                     + wredB[h & 1][2][ti] + wredB[h & 1][3][ti];
            float inv = 1.0f / gs;
            float g = gps[ti][h];
            acc0[ti] += pex0[ti] * inv * g;
            acc1[ti] += pex1[ti] * inv * g;
            mace[ti] += g * inv;
        }
    }
    #pragma unroll
    for (int ti = 0; ti < 8; ++ti) {
        int i = i0 + ti;
        float lm = NEGC + __logf(mace[ti]);
        float v0, v1;
        if (i >= len - 1) { v0 = NEGC; v1 = NEGC; }
        else {
            v0 = (j0 > i && j0 < len) ? __logf(acc0[ti]) : lm;
            v1 = (j1 > i && j1 < len) ? __logf(acc1[ti]) : lm;
        }
        out[((size_t)b*512 + i)*512 + j0] = v0;
        out[((size_t)b*512 + i)*512 + j1] = v1;
    }
}

// ---------------- vocab v2: bf16 logits -> in-place f32 log-softmax -----------
// ZERO LDS (row in 64 VGPR/thread); near the 786MB HBM floor (r11).
__global__ __launch_bounds__(256) void vocab_softmax_bf16(float* __restrict__ out) {
    __shared__ float red[8];
    size_t row = blockIdx.x;
    char* rowbase = (char*)out + row * (size_t)32000 * 4;
    const bf16x8* g8 = (const bf16x8*)rowbase;
    int t = threadIdx.x, wave = t >> 6, lane = t & 63;
    bf16x8 cc[16];
    float mx = -1e30f;
    #pragma unroll
    for (int s = 0; s < 16; ++s) {
        int v = t + s*256;
        if (v < 4000) {
            cc[s] = g8[v];
            #pragma unroll
            for (int jj = 0; jj < 8; ++jj) mx = fmaxf(mx, (float)cc[s][jj]);
        }
    }
    #pragma unroll
    for (int o = 32; o; o >>= 1) mx = fmaxf(mx, __shfl_xor(mx, o));
    if (lane == 0) red[wave] = mx;
    __syncthreads();
    mx = fmaxf(fmaxf(red[0], red[1]), fmaxf(red[2], red[3]));
    float sum = 0.f;
    #pragma unroll
    for (int s = 0; s < 16; ++s) {
        int v = t + s*256;
        if (v < 4000) {
            #pragma unroll
            for (int jj = 0; jj < 8; ++jj) sum += __expf((float)cc[s][jj] - mx);
        }
    }
    #pragma unroll
    for (int o = 32; o; o >>= 1) sum += __shfl_xor(sum, o);
    if (lane == 0) red[4 + wave] = sum;
    __syncthreads();               // also orders ALL reads before writes below
    float lse = mx + __logf(red[4] + red[5] + red[6] + red[7]);
    float4* o4 = (float4*)rowbase;
    #pragma unroll
    for (int s = 0; s < 16; ++s) {
        int v = t + s*256;
        if (v < 4000) {
            float4 a, b;
            a.x = (float)cc[s][0] - lse; a.y = (float)cc[s][1] - lse;
            a.z = (float)cc[s][2] - lse; a.w = (float)cc[s][3] - lse;
            b.x = (float)cc[s][4] - lse; b.y = (float)cc[s][5] - lse;
            b.z = (float)cc[s][6] - lse; b.w = (float)cc[s][7] - lse;
            o4[v*2]   = a;
            o4[v*2+1] = b;
        }
    }
}

extern "C" void kernel_launch(void* const* d_in, const int* in_sizes, int n_in,
                              void* d_out, int out_size, void* d_ws, size_t ws_size,
                              hipStream_t stream) {
    (void)in_sizes; (void)n_in; (void)out_size; (void)ws_size;
    const float* x      = (const float*)d_in[0];
    const int*   lens   = (const int*)  d_in[1];
    const float* ln_g   = (const float*)d_in[2];
    const float* ln_b   = (const float*)d_in[3];
    const float* attn_A = (const float*)d_in[4];
    const float* attn_S = (const float*)d_in[5];
    const float* attn_b = (const float*)d_in[6];
    const float* gate_A = (const float*)d_in[7];
    const float* gate_S = (const float*)d_in[8];
    const float* gate_b = (const float*)d_in[9];
    const float* lm_A   = (const float*)d_in[10];
    const float* lm_S   = (const float*)d_in[11];
    const float* lm_b   = (const float*)d_in[12];

    float* out_trans = (float*)d_out;
    float* out_vocab = out_trans + (size_t)8*512*512;

    char* ws = (char*)d_ws;
    __bf16*        xn      = (__bf16*)(ws);                   //  8,388,608 B
    unsigned char* xn8     = (unsigned char*)(ws + 8388608);  //  4,194,304 B (fp8)
    unsigned char* WtAttn8 = (unsigned char*)(ws + 12582912); //  2,097,152 B (fp8 x16)
    unsigned char* WtLm8   = (unsigned char*)(ws + 14680064); // 32,768,000 B (fp8 x16)
    float*         Wg      = (float*)(ws + 47448064);         //     65,536 B
    float*         qkbuf   = (float*)(ws + 47513600);         // 33,554,432 B
    float*         Gp      = (float*)(ws + 81068032);         //    262,144 B

    hipLaunchKernelGGL(ln_kernel,    dim3(4096),     dim3(256), 0, stream, x, ln_g, ln_b, xn, xn8);
    hipLaunchKernelGGL(gatew_kernel, dim3(64),       dim3(256), 0, stream, gate_A, gate_S, Wg);
    hipLaunchKernelGGL((phm_build<1>), dim3(8, 8),   dim3(256), 0, stream, attn_A, attn_S, (void*)WtAttn8, 4, 256, 512);
    hipLaunchKernelGGL((phm_build<1>), dim3(250, 16),dim3(256), 0, stream, lm_A, lm_S, (void*)WtLm8, 2, 512, 16000);
    hipLaunchKernelGGL((gemm_mx<0,0>), dim3(16, 32), dim3(256), 0, stream,
                       xn8, WtAttn8, attn_b, (void*)qkbuf, 2048, 1024);
    hipLaunchKernelGGL(gate_kernel,  dim3(4096),     dim3(256), 0, stream, xn, Wg, gate_b, Gp);
    hipLaunchKernelGGL(scores_kernel,dim3(512),      dim3(256), 0, stream, qkbuf, Gp, lens, out_trans);
    hipLaunchKernelGGL((gemm_mx<1,1>), dim3(8000),   dim3(256), 0, stream,
                       xn8, WtLm8, lm_b, (void*)out_vocab, 32000, 1024);
    hipLaunchKernelGGL(vocab_softmax_bf16, dim3(4096), dim3(256), 0, stream, out_vocab);
}